// Round 3
// baseline (214.350 us; speedup 1.0000x reference)
//
#include <hip/hip_runtime.h>
#include <hip/hip_bf16.h>

#define NATOMS 50000
#define NEDGES 100000
#define AD 64
#define BD 16
#define PITCH 1096           // LDS row pitch in bf16 elems (1088 + 8)
#define MTILE 256
#define NTILES ((NEDGES + MTILE - 1) / MTILE)   // 391
#define NGROUPS (NTILES * 8)                    // 3128 wave-groups of 32 edges
#define NSLOTS (NGROUPS * 2)                    // head+tail partial slot per group
#define WS_NEEDED ((size_t)NSLOTS * 64 * sizeof(float) + (size_t)NSLOTS * sizeof(int))

typedef __bf16 bf16x8 __attribute__((ext_vector_type(8)));
typedef __bf16 bf16x4 __attribute__((ext_vector_type(4)));
typedef float  f32x16 __attribute__((ext_vector_type(16)));

template<bool USE_WS>
__global__ __launch_bounds__(512, 1)
void edgenet_kernel(const float* __restrict__ atom,   // 50000 x 64
                    const float* __restrict__ bond,   // 100000 x 16
                    const int*   __restrict__ pair,   // 100000 x 2 (tgt, nbr) int32
                    const float* __restrict__ kern,   // 16 x 4096
                    const float* __restrict__ bias,   // 4096
                    float* __restrict__ out,          // 50000 x 64 (pre-zeroed)
                    float* __restrict__ wsData,       // NSLOTS x 64 partial rows
                    int*   __restrict__ wsTgt)        // NSLOTS tags (-1 = empty)
{
    __shared__ __bf16 Blds[64 * PITCH];   // B[i][k], k in [0,1088)

    const int tid = threadIdx.x;

    // ---- stage B = [kernel | bias] into LDS as bf16 ----
    for (int q = tid; q < (16 * 4096) / 4; q += 512) {
        const int idx = q * 4;                  // flat index: b*4096 + i*64 + j
        const int b = idx >> 12;
        const int i = (idx >> 6) & 63;
        const int j = idx & 63;
        const float4 v = *reinterpret_cast<const float4*>(kern + idx);
        bf16x4 w;
        w[0] = (__bf16)v.x; w[1] = (__bf16)v.y; w[2] = (__bf16)v.z; w[3] = (__bf16)v.w;
        *reinterpret_cast<bf16x4*>(Blds + i * PITCH + (b << 6) + j) = w;
    }
    for (int q = tid; q < 4096 / 4; q += 512) {
        const int idx = q * 4;
        const int i = idx >> 6;
        const int j = idx & 63;
        const float4 v = *reinterpret_cast<const float4*>(bias + idx);
        bf16x4 w;
        w[0] = (__bf16)v.x; w[1] = (__bf16)v.y; w[2] = (__bf16)v.z; w[3] = (__bf16)v.w;
        *reinterpret_cast<bf16x4*>(Blds + i * PITCH + 1024 + j) = w;
    }
    __syncthreads();

    const int wave = tid >> 6;
    const int lane = tid & 63;
    const int l31  = lane & 31;
    const int half = lane >> 5;     // k-half for fragments / feature-half for C
    const int h8   = half * 8;

    const __bf16* __restrict__ Brow0 = Blds + l31 * PITCH;         // features 0..31
    const __bf16* __restrict__ Brow1 = Blds + (32 + l31) * PITCH;  // features 32..63

    for (int tile = blockIdx.x; tile < NTILES; tile += gridDim.x) {
        const int eb = tile * MTILE + wave * 32;  // this wave's 32 contiguous edges
        const bool validG = (eb < NEDGES);        // NEDGES % 32 == 0: group all-valid or all-invalid
        const int eA = eb + l31;
        const bool validE = (eA < NEDGES);
        const float scale = validE ? 1.0f : 0.0f;
        const int eAc = validE ? eA : 0;

        int ni = pair[2 * eAc + 1];
        if ((unsigned)ni >= NATOMS) ni = 0;
        const float* nbrRow  = atom + (long)ni * AD;
        const float* bondRow = bond + (long)eAc * BD;

        // preload the half-row of nbr this lane needs: j = 16q + 8*half + r
        float nb[4][8];
        #pragma unroll
        for (int q = 0; q < 4; ++q) {
            const float4 lo = *reinterpret_cast<const float4*>(nbrRow + q * 16 + h8);
            const float4 hi = *reinterpret_cast<const float4*>(nbrRow + q * 16 + h8 + 4);
            nb[q][0] = lo.x * scale; nb[q][1] = lo.y * scale;
            nb[q][2] = lo.z * scale; nb[q][3] = lo.w * scale;
            nb[q][4] = hi.x * scale; nb[q][5] = hi.y * scale;
            nb[q][6] = hi.z * scale; nb[q][7] = hi.w * scale;
        }
        float bd[16];
        #pragma unroll
        for (int q = 0; q < 4; ++q) {
            const float4 v = *reinterpret_cast<const float4*>(bondRow + q * 4);
            bd[q * 4 + 0] = v.x; bd[q * 4 + 1] = v.y;
            bd[q * 4 + 2] = v.z; bd[q * 4 + 3] = v.w;
        }

        f32x16 acc0, acc1;   // C[feature][edge]: edge = l31, feature = (r&3)+8*(r>>2)+4*half (+32 for acc1)
        #pragma unroll
        for (int r = 0; r < 16; ++r) { acc0[r] = 0.f; acc1[r] = 0.f; }

        // main K: k = 16t + 8*half + r ;  b = t>>2 ; j = 16*(t&3) + 8*half + r
        #pragma unroll
        for (int t = 0; t < 64; ++t) {
            const float bv = bd[t >> 2];
            bf16x8 a;
            #pragma unroll
            for (int r = 0; r < 8; ++r) a[r] = (__bf16)(bv * nb[t & 3][r]);
            const int k0 = t * 16 + h8;
            const bf16x8 b0 = *reinterpret_cast<const bf16x8*>(Brow0 + k0);
            const bf16x8 b1 = *reinterpret_cast<const bf16x8*>(Brow1 + k0);
            // swapped operands: A-op = Bmat feature rows, B-op = per-edge vector
            acc0 = __builtin_amdgcn_mfma_f32_32x32x16_bf16(b0, a, acc0, 0, 0, 0);
            acc1 = __builtin_amdgcn_mfma_f32_32x32x16_bf16(b1, a, acc1, 0, 0, 0);
        }
        // bias rows: k = 1024.. ; A-side per-edge vector = nbr (scaled)
        #pragma unroll
        for (int t = 64; t < 68; ++t) {
            bf16x8 a;
            #pragma unroll
            for (int r = 0; r < 8; ++r) a[r] = (__bf16)(nb[t - 64][r]);
            const int k0 = t * 16 + h8;
            const bf16x8 b0 = *reinterpret_cast<const bf16x8*>(Brow0 + k0);
            const bf16x8 b1 = *reinterpret_cast<const bf16x8*>(Brow1 + k0);
            acc0 = __builtin_amdgcn_mfma_f32_32x32x16_bf16(b0, a, acc0, 0, 0, 0);
            acc1 = __builtin_amdgcn_mfma_f32_32x32x16_bf16(b1, a, acc1, 0, 0, 0);
        }

        // ---- segmented inclusive scan over sorted tgt within the 32-edge group ----
        const int myTgt = validE ? pair[2 * eA] : 0x7fffffff;

        #pragma unroll
        for (int d = 1; d < 32; d <<= 1) {
            const int srcTgt = __shfl_up(myTgt, (unsigned)d, 32);
            const bool same = (l31 >= d) && (srcTgt == myTgt);
            #pragma unroll
            for (int r = 0; r < 16; ++r) {
                const float v0 = __shfl_up(acc0[r], (unsigned)d, 32);
                const float v1 = __shfl_up(acc1[r], (unsigned)d, 32);
                if (same) { acc0[r] += v0; acc1[r] += v1; }
            }
        }

        // ---- classify segment-last lanes; route to out / workspace ----
        const int nTgt = __shfl_down(myTgt, 1u, 32);
        const bool isLast = validE && ((l31 == 31) || (nTgt != myTgt));

        int prevTgt = -1, nextTgt = -1;
        if (validG) {
            prevTgt = (eb > 0) ? pair[2 * (eb - 1)] : -1;
            nextTgt = (eb + 32 < NEDGES) ? pair[2 * (eb + 32)] : -1;
        }
        const bool crossH = isLast && (myTgt == prevTgt);
        const bool crossT = isLast && (myTgt == nextTgt);

        if (USE_WS) {
            const bool toHead   = crossH;               // both-crossing -> head slot
            const bool toTail   = crossT && !crossH;
            const bool interior = isLast && !crossH && !crossT;
            const int  gslot    = (tile * 8 + wave) * 2;

            float* dst = nullptr;
            if (interior)    dst = out + (long)myTgt * AD;
            else if (toHead) dst = wsData + (long)gslot * 64;
            else if (toTail) dst = wsData + (long)(gslot + 1) * 64;

            if (dst) {
                #pragma unroll
                for (int rq = 0; rq < 4; ++rq) {
                    float4 v0, v1;
                    v0.x = acc0[rq*4+0]; v0.y = acc0[rq*4+1]; v0.z = acc0[rq*4+2]; v0.w = acc0[rq*4+3];
                    v1.x = acc1[rq*4+0]; v1.y = acc1[rq*4+1]; v1.z = acc1[rq*4+2]; v1.w = acc1[rq*4+3];
                    *reinterpret_cast<float4*>(dst + 8 * rq + 4 * half)      = v0;
                    *reinterpret_cast<float4*>(dst + 32 + 8 * rq + 4 * half) = v1;
                }
                if (half == 0 && toHead) wsTgt[gslot]     = myTgt;
                if (half == 0 && toTail) wsTgt[gslot + 1] = myTgt;
            }
            // mark unused slots empty (exactly once, by lane 0)
            const bool anyH = __any(toHead);
            const bool anyT = __any(toTail);
            if (lane == 0) {
                if (!anyH) wsTgt[gslot]     = -1;
                if (!anyT) wsTgt[gslot + 1] = -1;
            }
        } else {
            // fallback: all-atomic after scan (no workspace)
            if (isLast) {
                float* o = out + (long)myTgt * AD;
                #pragma unroll
                for (int r = 0; r < 16; ++r) {
                    const int f = (r & 3) + 8 * (r >> 2) + 4 * half;
                    atomicAdd(o + f,      acc0[r]);
                    atomicAdd(o + 32 + f, acc1[r]);
                }
            }
        }
    }
}

// One wave per slot: the first slot of each equal-tgt run sums the run and
// stores the output row. Runs are contiguous in slot order (tgt sorted),
// possibly with -1 holes inside.
__global__ __launch_bounds__(256)
void cleanup_kernel(const float* __restrict__ wsData,
                    const int*   __restrict__ wsTgt,
                    float* __restrict__ out)
{
    const int w    = (int)((blockIdx.x * blockDim.x + threadIdx.x) >> 6);
    const int lane = threadIdx.x & 63;
    if (w >= NSLOTS) return;
    const int tgt = wsTgt[w];
    if (tgt < 0) return;

    // ownership: nearest earlier non-empty slot must have a different tgt
    for (int p = w - 1; p >= 0; --p) {
        const int t = wsTgt[p];
        if (t == tgt) return;      // not the run head
        if (t >= 0) break;
    }

    float v = wsData[(long)w * 64 + lane];
    for (int q = w + 1; q < NSLOTS; ++q) {
        const int t = wsTgt[q];
        if (t < 0) continue;
        if (t != tgt) break;
        v += wsData[(long)q * 64 + lane];
    }
    out[(long)tgt * AD + lane] = v;
}

extern "C" void kernel_launch(void* const* d_in, const int* in_sizes, int n_in,
                              void* d_out, int out_size, void* d_ws, size_t ws_size,
                              hipStream_t stream) {
    const float* atom = (const float*)d_in[0];
    const float* bond = (const float*)d_in[1];
    const int*   pair = (const int*)d_in[2];
    const float* kern = (const float*)d_in[3];
    const float* bias = (const float*)d_in[4];
    float* out = (float*)d_out;

    hipMemsetAsync(d_out, 0, (size_t)out_size * sizeof(float), stream);

    const int grid = NTILES < 256 ? NTILES : 256;
    if (ws_size >= WS_NEEDED) {
        float* wsData = (float*)d_ws;
        int*   wsTgt  = (int*)((char*)d_ws + (size_t)NSLOTS * 64 * sizeof(float));
        edgenet_kernel<true><<<grid, 512, 0, stream>>>(atom, bond, pair, kern, bias,
                                                       out, wsData, wsTgt);
        const int thr = NSLOTS * 64;
        cleanup_kernel<<<(thr + 255) / 256, 256, 0, stream>>>(wsData, wsTgt, out);
    } else {
        edgenet_kernel<false><<<grid, 512, 0, stream>>>(atom, bond, pair, kern, bias,
                                                        out, nullptr, nullptr);
    }
}

// Round 4
// 61.246 us; speedup vs baseline: 3.4998x; 3.4998x over previous
//
#include <hip/hip_runtime.h>
#include <hip/hip_bf16.h>
#include <climits>

#define NATOMS 50000
#define NEDGES 100000
#define AD 64
#define BD 16
#define PITCH 1096           // LDS row pitch in bf16 elems (1088 + 8)
#define MTILE 256
#define NTILES ((NEDGES + MTILE - 1) / MTILE)   // 391

typedef __bf16 bf16x8 __attribute__((ext_vector_type(8)));
typedef __bf16 bf16x4 __attribute__((ext_vector_type(4)));
typedef float  f32x16 __attribute__((ext_vector_type(16)));

// MFMA + in-wave segmented scan over one 32-edge slot [gstart, gstart+32) ∩ [, segEnd)
__device__ __forceinline__ void scan_slot(
    const int gstart, const int segEnd,
    const float* __restrict__ atom, const float* __restrict__ bond,
    const int* __restrict__ pair,
    const __bf16* __restrict__ Brow0, const __bf16* __restrict__ Brow1,
    const int l31, const int half, const int h8,
    f32x16& acc0, f32x16& acc1, int& myTgt, bool& isOwner, bool& contin)
{
    const int eA = gstart + l31;
    const bool validE = (eA < segEnd);
    const float scale = validE ? 1.0f : 0.0f;
    const int eAc = validE ? eA : 0;

    int ni = pair[2 * eAc + 1];
    if ((unsigned)ni >= NATOMS) ni = 0;
    const float* nbrRow  = atom + (long)ni * AD;
    const float* bondRow = bond + (long)eAc * BD;

    // preload the half-row of nbr this lane needs: j = 16q + 8*half + r
    float nb[4][8];
    #pragma unroll
    for (int q = 0; q < 4; ++q) {
        const float4 lo = *reinterpret_cast<const float4*>(nbrRow + q * 16 + h8);
        const float4 hi = *reinterpret_cast<const float4*>(nbrRow + q * 16 + h8 + 4);
        nb[q][0] = lo.x * scale; nb[q][1] = lo.y * scale;
        nb[q][2] = lo.z * scale; nb[q][3] = lo.w * scale;
        nb[q][4] = hi.x * scale; nb[q][5] = hi.y * scale;
        nb[q][6] = hi.z * scale; nb[q][7] = hi.w * scale;
    }
    float bd[16];
    #pragma unroll
    for (int q = 0; q < 4; ++q) {
        const float4 v = *reinterpret_cast<const float4*>(bondRow + q * 4);
        bd[q * 4 + 0] = v.x; bd[q * 4 + 1] = v.y;
        bd[q * 4 + 2] = v.z; bd[q * 4 + 3] = v.w;
    }

    #pragma unroll
    for (int r = 0; r < 16; ++r) { acc0[r] = 0.f; acc1[r] = 0.f; }

    // main K: k = 16t + 8*half + r ;  b = t>>2 ; j = 16*(t&3) + 8*half + r
    #pragma unroll
    for (int t = 0; t < 64; ++t) {
        const float bv = bd[t >> 2];
        bf16x8 a;
        #pragma unroll
        for (int r = 0; r < 8; ++r) a[r] = (__bf16)(bv * nb[t & 3][r]);
        const int k0 = t * 16 + h8;
        const bf16x8 b0 = *reinterpret_cast<const bf16x8*>(Brow0 + k0);
        const bf16x8 b1 = *reinterpret_cast<const bf16x8*>(Brow1 + k0);
        // swapped operands: C[feature][edge], edge = l31
        acc0 = __builtin_amdgcn_mfma_f32_32x32x16_bf16(b0, a, acc0, 0, 0, 0);
        acc1 = __builtin_amdgcn_mfma_f32_32x32x16_bf16(b1, a, acc1, 0, 0, 0);
    }
    #pragma unroll
    for (int t = 64; t < 68; ++t) {   // bias rows, A-side vector = nbr (scaled)
        bf16x8 a;
        #pragma unroll
        for (int r = 0; r < 8; ++r) a[r] = (__bf16)(nb[t - 64][r]);
        const int k0 = t * 16 + h8;
        const bf16x8 b0 = *reinterpret_cast<const bf16x8*>(Brow0 + k0);
        const bf16x8 b1 = *reinterpret_cast<const bf16x8*>(Brow1 + k0);
        acc0 = __builtin_amdgcn_mfma_f32_32x32x16_bf16(b0, a, acc0, 0, 0, 0);
        acc1 = __builtin_amdgcn_mfma_f32_32x32x16_bf16(b1, a, acc1, 0, 0, 0);
    }

    // segmented inclusive scan over sorted tgt within the 32-lane group
    myTgt = validE ? pair[2 * eA] : INT_MAX;
    #pragma unroll
    for (int d = 1; d < 32; d <<= 1) {
        const int srcTgt = __shfl_up(myTgt, (unsigned)d, 32);
        const bool same = (l31 >= d) && (srcTgt == myTgt);
        #pragma unroll
        for (int r = 0; r < 16; ++r) {
            const float v0 = __shfl_up(acc0[r], (unsigned)d, 32);
            const float v1 = __shfl_up(acc1[r], (unsigned)d, 32);
            if (same) { acc0[r] += v0; acc1[r] += v1; }
        }
    }

    const int nTgt = __shfl_down(myTgt, 1u, 32);
    const bool isLast = validE && ((l31 == 31) || (nTgt != myTgt));
    const int nextHead = (gstart + 32 < segEnd) ? pair[2 * (gstart + 32)] : INT_MIN;
    contin  = validE && (l31 == 31) && (myTgt == nextHead);
    isOwner = isLast && !contin;
}

// add matching tail-partials from earlier slots, then plain-store the row
__device__ __forceinline__ void emit_row(
    float* __restrict__ out, const float (*Trow)[64], const int* __restrict__ Ttag,
    const int wlimit, const int myTgt, const int half,
    f32x16& acc0, f32x16& acc1)
{
    for (int w2 = 0; w2 < wlimit; ++w2) {
        if (Ttag[w2] == myTgt) {
            #pragma unroll
            for (int r = 0; r < 16; ++r) {
                const int f = (r & 3) + 8 * (r >> 2) + 4 * half;
                acc0[r] += Trow[w2][f];
                acc1[r] += Trow[w2][f + 32];
            }
        }
    }
    float* o = out + (long)myTgt * AD;
    #pragma unroll
    for (int rq = 0; rq < 4; ++rq) {
        float4 v0, v1;
        v0.x = acc0[rq*4+0]; v0.y = acc0[rq*4+1]; v0.z = acc0[rq*4+2]; v0.w = acc0[rq*4+3];
        v1.x = acc1[rq*4+0]; v1.y = acc1[rq*4+1]; v1.z = acc1[rq*4+2]; v1.w = acc1[rq*4+3];
        *reinterpret_cast<float4*>(o + 8 * rq + 4 * half)      = v0;
        *reinterpret_cast<float4*>(o + 32 + 8 * rq + 4 * half) = v1;
    }
}

__global__ __launch_bounds__(512, 1)
void edgenet_kernel(const float* __restrict__ atom,
                    const float* __restrict__ bond,
                    const int*   __restrict__ pair,
                    const float* __restrict__ kern,
                    const float* __restrict__ bias,
                    float* __restrict__ out)
{
    __shared__ __bf16 Blds[64 * PITCH];   // B[i][k], k in [0,1088)
    __shared__ float  Trow[8][64];        // per-slot continuing tail partial rows
    __shared__ int    Ttag[8];            // tgt tag of each tail partial (INT_MIN = none)
    __shared__ int    SE[2];              // [s, e) segment-aligned tile bounds

    const int tid = threadIdx.x;

    // ---- stage B = [kernel | bias] into LDS as bf16 ----
    for (int q = tid; q < (16 * 4096) / 4; q += 512) {
        const int idx = q * 4;                  // flat: b*4096 + i*64 + j
        const int b = idx >> 12;
        const int i = (idx >> 6) & 63;
        const int j = idx & 63;
        const float4 v = *reinterpret_cast<const float4*>(kern + idx);
        bf16x4 w;
        w[0] = (__bf16)v.x; w[1] = (__bf16)v.y; w[2] = (__bf16)v.z; w[3] = (__bf16)v.w;
        *reinterpret_cast<bf16x4*>(Blds + i * PITCH + (b << 6) + j) = w;
    }
    for (int q = tid; q < 4096 / 4; q += 512) {
        const int idx = q * 4;
        const int i = idx >> 6;
        const int j = idx & 63;
        const float4 v = *reinterpret_cast<const float4*>(bias + idx);
        bf16x4 w;
        w[0] = (__bf16)v.x; w[1] = (__bf16)v.y; w[2] = (__bf16)v.z; w[3] = (__bf16)v.w;
        *reinterpret_cast<bf16x4*>(Blds + i * PITCH + 1024 + j) = w;
    }

    const int wave = tid >> 6;
    const int lane = tid & 63;
    const int l31  = lane & 31;
    const int half = lane >> 5;
    const int h8   = half * 8;

    const __bf16* __restrict__ Brow0 = Blds + l31 * PITCH;
    const __bf16* __restrict__ Brow1 = Blds + (32 + l31) * PITCH;

    for (int tile = blockIdx.x; tile < NTILES; tile += gridDim.x) {
        // ---- segment-aligned bounds: s = firstBreak(tile*256), e = firstBreak((tile+1)*256)
        if (wave == 0) {
            const int p0 = tile * MTILE;
            int p1 = p0 + MTILE; if (p1 > NEDGES) p1 = NEDGES;
            const int q = (lane < 32) ? (p0 + lane) : (p1 + (lane - 32));
            bool brk;
            if (q <= 0 || q >= NEDGES) brk = true;
            else brk = (pair[2 * q] != pair[2 * (q - 1)]);
            const unsigned long long m = __ballot(brk);
            if (lane == 0) {
                const unsigned lo = (unsigned)(m & 0xffffffffull);
                const unsigned hi = (unsigned)(m >> 32);
                SE[0] = p0 + (lo ? (int)__builtin_ctz(lo) : 32);
                SE[1] = p1 + (hi ? (int)__builtin_ctz(hi) : 32);
            }
        }
        __syncthreads();
        const int s = SE[0];
        const int e = SE[1];

        // ---- slots 0..7: MFMA + scan ----
        f32x16 acc0, acc1; int myTgt; bool isOwner, contin;
        scan_slot(s + wave * 32, e, atom, bond, pair, Brow0, Brow1,
                  l31, half, h8, acc0, acc1, myTgt, isOwner, contin);

        // tail-partial handoff (wave w -> later waves)
        if (l31 == 31) {
            if (contin) {
                #pragma unroll
                for (int r = 0; r < 16; ++r) {
                    const int f = (r & 3) + 8 * (r >> 2) + 4 * half;
                    Trow[wave][f]      = acc0[r];
                    Trow[wave][f + 32] = acc1[r];
                }
            }
            if (half == 0) Ttag[wave] = contin ? myTgt : INT_MIN;
        }
        __syncthreads();

        if (isOwner) emit_row(out, Trow, Ttag, wave, myTgt, half, acc0, acc1);

        // ---- slot 8 (range overhang, <= 31 edges): wave 7 only ----
        if (wave == 7) {
            const int g8 = s + 8 * 32;
            if (g8 < e) {
                scan_slot(g8, e, atom, bond, pair, Brow0, Brow1,
                          l31, half, h8, acc0, acc1, myTgt, isOwner, contin);
                if (isOwner) emit_row(out, Trow, Ttag, 8, myTgt, half, acc0, acc1);
            }
        }
        __syncthreads();   // protect SE / Trow / Ttag before next tile
    }
}

extern "C" void kernel_launch(void* const* d_in, const int* in_sizes, int n_in,
                              void* d_out, int out_size, void* d_ws, size_t ws_size,
                              hipStream_t stream) {
    const float* atom = (const float*)d_in[0];
    const float* bond = (const float*)d_in[1];
    const int*   pair = (const int*)d_in[2];
    const float* kern = (const float*)d_in[3];
    const float* bias = (const float*)d_in[4];
    float* out = (float*)d_out;

    hipMemsetAsync(d_out, 0, (size_t)out_size * sizeof(float), stream);

    const int grid = NTILES < 256 ? NTILES : 256;
    edgenet_kernel<<<grid, 512, 0, stream>>>(atom, bond, pair, kern, bias, out);
}